// Round 16
// baseline (398.668 us; speedup 1.0000x reference)
//
#include <hip/hip_runtime.h>
#include <hip/hip_bf16.h>

#define D 128
#define SCAN_C 512
#define BKT 512        // nodes per bucket
#define BKT_SHIFT 9
#define CH 256         // edge chunks
#define NBMAX 512
#define MREP 64        // min-buffer replicas

typedef __attribute__((ext_vector_type(8))) short bf16x8;
typedef __attribute__((ext_vector_type(4))) float f32x4;

// ---------------- bf16 helpers (manual, RN-even) ----------------
__device__ __forceinline__ float bf16_to_f(unsigned int u) {
    union { unsigned int i; float f; } c; c.i = u << 16; return c.f;
}
__device__ __forceinline__ unsigned short f_to_bf16(float f) {
    union { float f; unsigned int i; } c; c.f = f;
    unsigned int r = c.i + 0x7FFFu + ((c.i >> 16) & 1u);
    return (unsigned short)(r >> 16);
}

// ---------------- runtime dtype detection ----------------
__global__ void detect_kernel(const unsigned short* __restrict__ xr,
                              const int* __restrict__ er, int* __restrict__ flag) {
    int plaus = 0;
    for (int i = 0; i < 64; ++i) {
        unsigned short u = xr[2 * i];
        int e = (u >> 7) & 0xFF;
        if (e >= 0x74 && e <= 0x82) plaus++;
    }
    flag[1] = (plaus >= 32) ? 1 : 0;
    int zeros = 0;
    for (int i = 1; i < 128; i += 2) zeros += (er[i] == 0);
    flag[0] = (zeros >= 60) ? 1 : 0;
}

__device__ __forceinline__ int load_idx(const void* p, long long i, int is64) {
    if (is64) return (int)((const long long*)p)[i];
    return ((const int*)p)[i];
}

// ---------------- fused prolog: packW + bias cvt + minbuf init + x cvt ----------------
// blocks 0..47: pack W into MFMA B-fragment order
// block 48:     bias -> fp32, minbuf -> +inf encoding
// blocks 49+ :  x -> bf16 copy (fp32 input only; no-op when input already bf16)
__global__ void prep_kernel(const void* __restrict__ x0, const void* __restrict__ Wl0,
                            const void* __restrict__ Wr0, const void* __restrict__ bl0,
                            const int* __restrict__ flag,
                            unsigned short* __restrict__ Wpack, float* __restrict__ blf,
                            unsigned int* __restrict__ minbuf, unsigned short* __restrict__ xb,
                            int L, int nx) {
    const int is_bf16 = flag[1];
    const int b = blockIdx.x;
    const int t = threadIdx.x;

    if (b < 48) {                       // ---- packW ----
        int idx = b * 256 + t;
        if (idx >= L * 8 * 8 * 64) return;
        int lane = idx & 63;
        int ks = (idx >> 6) & 7;
        int nt = (idx >> 9) & 7;
        int layer = idx >> 12;
        int n = nt * 16 + (lane & 15);
        int k0 = ks * 32 + (lane >> 4) * 8;
        unsigned short outv[8];
#pragma unroll
        for (int j = 0; j < 8; ++j) {
            int k = k0 + j;
            size_t off = (size_t)layer * D * D + (size_t)n * D + (k & 127);
            float v;
            if (is_bf16) {
                const unsigned short* W = (const unsigned short*)((k < D) ? Wl0 : Wr0);
                v = bf16_to_f(W[off]);
            } else {
                const float* W = (const float*)((k < D) ? Wl0 : Wr0);
                v = W[off];
            }
            outv[j] = f_to_bf16(v);
        }
        *(uint4*)&Wpack[(size_t)idx * 8] = *(uint4*)outv;
        return;
    }
    if (b == 48) {                      // ---- bias + minbuf init ----
        for (int i = t; i < L * D; i += 256) {
            if (is_bf16) blf[i] = bf16_to_f(((const unsigned short*)bl0)[i]);
            else         blf[i] = ((const float*)bl0)[i];
        }
        for (int i = t; i < MREP * D; i += 256) minbuf[i] = 0xFFFFFFFFu;
        return;
    }
    // ---- x conversion (fp32 input only) ----
    if (is_bf16) return;
    const float* s = (const float*)x0;
    int i = (b - 49) * 256 + t;
    int stride = (gridDim.x - 49) * 256;
    for (; i < nx; i += stride) xb[i] = f_to_bf16(s[i]);
}

// ---------------- bucketed CSR build ----------------
__global__ void bucket_hist_kernel(const void* __restrict__ eidx, const int* __restrict__ flag,
                                   int* __restrict__ counts2D, int E, int NB, int EPC) {
    __shared__ int hist[NBMAX];
    int c = blockIdx.x;
    for (int i = threadIdx.x; i < NB; i += blockDim.x) hist[i] = 0;
    __syncthreads();
    int is64 = flag[0];
    int end = min(E, (c + 1) * EPC);
    for (int e = c * EPC + threadIdx.x; e < end; e += blockDim.x) {
        int d = load_idx(eidx, (long long)E + e, is64);
        atomicAdd(&hist[d >> BKT_SHIFT], 1);
    }
    __syncthreads();
    for (int i = threadIdx.x; i < NB; i += blockDim.x)
        counts2D[i * CH + c] = hist[i];
}

__global__ void gscan1_kernel(const int* __restrict__ in, int* __restrict__ blockSums, int n) {
    __shared__ int red[256];
    int base = blockIdx.x * SCAN_C;
    int t = threadIdx.x;
    int s = 0;
    if (base + t < n) s += in[base + t];
    if (base + t + 256 < n) s += in[base + t + 256];
    red[t] = s;
    __syncthreads();
    for (int off = 128; off > 0; off >>= 1) {
        if (t < off) red[t] += red[t + off];
        __syncthreads();
    }
    if (t == 0) blockSums[blockIdx.x] = red[0];
}

__global__ void gscan2_kernel(int* __restrict__ blockSums, int nb) {
    __shared__ int sh[256];
    int t = threadIdx.x;
    int orig = (t < nb) ? blockSums[t] : 0;
    sh[t] = orig;
    __syncthreads();
    for (int off = 1; off < 256; off <<= 1) {
        int v = (t >= off) ? sh[t - off] : 0;
        __syncthreads();
        sh[t] += v;
        __syncthreads();
    }
    if (t < nb) blockSums[t] = sh[t] - orig;
}

__global__ void gscan3_kernel(const int* __restrict__ in, const int* __restrict__ blockBase,
                              int* __restrict__ out, int n) {
    __shared__ int sh[SCAN_C];
    int base = blockIdx.x * SCAN_C;
    int t = threadIdx.x;
    int v0 = (base + t < n) ? in[base + t] : 0;
    int v1 = (base + t + 256 < n) ? in[base + t + 256] : 0;
    sh[t] = v0;
    sh[t + 256] = v1;
    __syncthreads();
    for (int off = 1; off < SCAN_C; off <<= 1) {
        int a = (t >= off) ? sh[t - off] : 0;
        int b = (t + 256 >= off) ? sh[t + 256 - off] : 0;
        __syncthreads();
        sh[t] += a;
        sh[t + 256] += b;
        __syncthreads();
    }
    int bb = blockBase[blockIdx.x];
    if (base + t < n) out[base + t] = bb + sh[t] - v0;
    if (base + t + 256 < n) out[base + t + 256] = bb + sh[t + 256] - v1;
}

__global__ void bucket_scatter_kernel(const void* __restrict__ eidx, const int* __restrict__ flag,
                                      const int* __restrict__ bases2D, unsigned int* __restrict__ ebuf,
                                      int E, int NB, int EPC) {
    __shared__ int cur[NBMAX];
    int c = blockIdx.x;
    for (int i = threadIdx.x; i < NB; i += blockDim.x) cur[i] = bases2D[i * CH + c];
    __syncthreads();
    int is64 = flag[0];
    int end = min(E, (c + 1) * EPC);
    for (int e = c * EPC + threadIdx.x; e < end; e += blockDim.x) {
        int s = load_idx(eidx, e, is64);
        int d = load_idx(eidx, (long long)E + e, is64);
        int b = d >> BKT_SHIFT;
        int pos = atomicAdd(&cur[b], 1);
        ebuf[pos] = ((unsigned)s << BKT_SHIFT) | (unsigned)(d & (BKT - 1));
    }
}

__global__ __launch_bounds__(BKT)
void bucket_csr_kernel(const unsigned int* __restrict__ ebuf, const int* __restrict__ bases2D,
                       int* __restrict__ offsets, int* __restrict__ srcs, int E, int N, int NB) {
    __shared__ int lcnt[BKT];
    __shared__ int sh[BKT];
    __shared__ int lcur[BKT];
    int b = blockIdx.x;
    int t = threadIdx.x;
    int start = bases2D[b * CH];
    int end = (b + 1 < NB) ? bases2D[(b + 1) * CH] : E;
    lcnt[t] = 0;
    __syncthreads();
    for (int e = start + t; e < end; e += BKT)
        atomicAdd(&lcnt[ebuf[e] & (BKT - 1)], 1);
    __syncthreads();
    sh[t] = lcnt[t];
    __syncthreads();
    for (int off = 1; off < BKT; off <<= 1) {
        int v = (t >= off) ? sh[t - off] : 0;
        __syncthreads();
        sh[t] += v;
        __syncthreads();
    }
    int excl = sh[t] - lcnt[t];
    int node = b * BKT + t;
    if (node < N) offsets[node] = start + excl;
    lcur[t] = start + excl;
    __syncthreads();
    for (int e = start + t; e < end; e += BKT) {
        unsigned int p = ebuf[e];
        int pos = atomicAdd(&lcur[p & (BKT - 1)], 1);
        srcs[pos] = (int)(p >> BKT_SHIFT);
    }
    if (b == 0 && t == 0) offsets[N] = E;
}

// ---------------- mean aggregation: 1 node per 16-lane group, edge-unroll-4 ----------------
__global__ void agg_kernel(const unsigned short* __restrict__ xmain,
                           const unsigned short* __restrict__ xalt,
                           const int* __restrict__ flag, const int* __restrict__ offsets,
                           const int* __restrict__ srcs, unsigned short* __restrict__ meanb, int N) {
    const unsigned short* xb = flag[1] ? xalt : xmain;
    int g = blockIdx.x * blockDim.x + threadIdx.x;
    int node = g >> 4;
    int lane = g & 15;
    if (node >= N) return;
    int beg = offsets[node], end = offsets[node + 1];
    float acc[8];
#pragma unroll
    for (int i = 0; i < 8; ++i) acc[i] = 0.f;
    const uint4* xp = (const uint4*)xb;

    int j = beg;
    for (; j + 3 < end; j += 4) {
        int s0 = srcs[j];
        int s1 = srcs[j + 1];
        int s2 = srcs[j + 2];
        int s3 = srcs[j + 3];
        uint4 v0 = xp[(size_t)s0 * 16 + lane];
        uint4 v1 = xp[(size_t)s1 * 16 + lane];
        uint4 v2 = xp[(size_t)s2 * 16 + lane];
        uint4 v3 = xp[(size_t)s3 * 16 + lane];
        acc[0] += bf16_to_f(v0.x & 0xFFFFu); acc[1] += bf16_to_f(v0.x >> 16);
        acc[2] += bf16_to_f(v0.y & 0xFFFFu); acc[3] += bf16_to_f(v0.y >> 16);
        acc[4] += bf16_to_f(v0.z & 0xFFFFu); acc[5] += bf16_to_f(v0.z >> 16);
        acc[6] += bf16_to_f(v0.w & 0xFFFFu); acc[7] += bf16_to_f(v0.w >> 16);
        acc[0] += bf16_to_f(v1.x & 0xFFFFu); acc[1] += bf16_to_f(v1.x >> 16);
        acc[2] += bf16_to_f(v1.y & 0xFFFFu); acc[3] += bf16_to_f(v1.y >> 16);
        acc[4] += bf16_to_f(v1.z & 0xFFFFu); acc[5] += bf16_to_f(v1.z >> 16);
        acc[6] += bf16_to_f(v1.w & 0xFFFFu); acc[7] += bf16_to_f(v1.w >> 16);
        acc[0] += bf16_to_f(v2.x & 0xFFFFu); acc[1] += bf16_to_f(v2.x >> 16);
        acc[2] += bf16_to_f(v2.y & 0xFFFFu); acc[3] += bf16_to_f(v2.y >> 16);
        acc[4] += bf16_to_f(v2.z & 0xFFFFu); acc[5] += bf16_to_f(v2.z >> 16);
        acc[6] += bf16_to_f(v2.w & 0xFFFFu); acc[7] += bf16_to_f(v2.w >> 16);
        acc[0] += bf16_to_f(v3.x & 0xFFFFu); acc[1] += bf16_to_f(v3.x >> 16);
        acc[2] += bf16_to_f(v3.y & 0xFFFFu); acc[3] += bf16_to_f(v3.y >> 16);
        acc[4] += bf16_to_f(v3.z & 0xFFFFu); acc[5] += bf16_to_f(v3.z >> 16);
        acc[6] += bf16_to_f(v3.w & 0xFFFFu); acc[7] += bf16_to_f(v3.w >> 16);
    }
    for (; j < end; ++j) {
        uint4 v = xp[(size_t)srcs[j] * 16 + lane];
        acc[0] += bf16_to_f(v.x & 0xFFFFu); acc[1] += bf16_to_f(v.x >> 16);
        acc[2] += bf16_to_f(v.y & 0xFFFFu); acc[3] += bf16_to_f(v.y >> 16);
        acc[4] += bf16_to_f(v.z & 0xFFFFu); acc[5] += bf16_to_f(v.z >> 16);
        acc[6] += bf16_to_f(v.w & 0xFFFFu); acc[7] += bf16_to_f(v.w >> 16);
    }

    float inv = (end > beg) ? 1.0f / (float)(end - beg) : 0.0f;
    uint4 o;
    o.x = (unsigned)f_to_bf16(acc[0] * inv) | ((unsigned)f_to_bf16(acc[1] * inv) << 16);
    o.y = (unsigned)f_to_bf16(acc[2] * inv) | ((unsigned)f_to_bf16(acc[3] * inv) << 16);
    o.z = (unsigned)f_to_bf16(acc[4] * inv) | ((unsigned)f_to_bf16(acc[5] * inv) << 16);
    o.w = (unsigned)f_to_bf16(acc[6] * inv) | ((unsigned)f_to_bf16(acc[7] * inv) << 16);
    ((uint4*)meanb)[(size_t)node * 16 + lane] = o;
}

// ---------------- MFMA dual GEMM, W staged in LDS ----------------
__global__ __launch_bounds__(512)
void gemm_mfma_kernel(const unsigned short* __restrict__ meanb,
                      const unsigned short* __restrict__ xmain,
                      const unsigned short* __restrict__ xalt,
                      const int* __restrict__ flag,
                      const unsigned short* __restrict__ Wpack, const float* __restrict__ bl,
                      unsigned short* __restrict__ outb, unsigned int* __restrict__ minbuf,
                      int N, int relu, int do_min) {
    __shared__ unsigned short Wlds[8 * 8 * 64 * 8];   // 64 KB; aliased as Otile in epilogue
    __shared__ float smin[8][D];
    const unsigned short* xb = flag[1] ? xalt : xmain;

    const int tid = threadIdx.x;
    const int wave = tid >> 6;            // 0..7
    const int lane = tid & 63;
    const int m16 = lane & 15;
    const int quad = lane >> 4;
    const int node0 = blockIdx.x * 128;
    const int arow = node0 + wave * 16 + m16;
    const bool rvalid = arow < N;

    {
        const uint4* wsrc = (const uint4*)Wpack;
        uint4* wdst = (uint4*)Wlds;
#pragma unroll
        for (int i = 0; i < 8; ++i) wdst[tid + i * 512] = wsrc[tid + i * 512];
    }
    __syncthreads();

    f32x4 acc[8];
#pragma unroll
    for (int i = 0; i < 8; ++i) acc[i] = (f32x4)0.0f;

#pragma unroll
    for (int ks = 0; ks < 8; ++ks) {
        uint4 tmp = make_uint4(0u, 0u, 0u, 0u);
        if (rvalid) {
            const unsigned short* base = (ks < 4)
                ? meanb + (size_t)arow * D + ks * 32 + quad * 8
                : xb    + (size_t)arow * D + (ks - 4) * 32 + quad * 8;
            tmp = *(const uint4*)base;
        }
        bf16x8 afrag = *(bf16x8*)&tmp;
#pragma unroll
        for (int nt = 0; nt < 8; ++nt) {
            bf16x8 bfrag = *(const bf16x8*)&Wlds[((nt * 8 + ks) * 64 + lane) * 8];
            acc[nt] = __builtin_amdgcn_mfma_f32_16x16x32_bf16(afrag, bfrag, acc[nt], 0, 0, 0);
        }
    }

    if (do_min) {
#pragma unroll
        for (int nt = 0; nt < 8; ++nt) {
            int n = nt * 16 + m16;
            float b = bl[n];
            float m = 3.402823466e38f;
#pragma unroll
            for (int r = 0; r < 4; ++r) {
                int node = node0 + wave * 16 + quad * 4 + r;
                float v = (node < N) ? (acc[nt][r] + b) : 3.402823466e38f;
                m = fminf(m, v);
            }
            m = fminf(m, __shfl_xor(m, 16, 64));
            m = fminf(m, __shfl_xor(m, 32, 64));
            if (quad == 0) smin[wave][n] = m;
        }
        __syncthreads();
        if (tid < D) {
            float m = smin[0][tid];
#pragma unroll
            for (int w = 1; w < 8; ++w) m = fminf(m, smin[w][tid]);
            unsigned bits = __float_as_uint(m);
            unsigned enc = ((int)bits >= 0) ? (bits ^ 0x80000000u) : ~bits;
            atomicMin(&minbuf[(blockIdx.x & (MREP - 1)) * D + tid], enc);
        }
        return;
    }

    __syncthreads();   // all ds_reads of Wlds complete before aliasing as Otile
    {
        unsigned short (*Ot)[136] = (unsigned short (*)[136])Wlds;
#pragma unroll
        for (int nt = 0; nt < 8; ++nt) {
            int n = nt * 16 + m16;
            float b = bl[n];
#pragma unroll
            for (int r = 0; r < 4; ++r) {
                int m = wave * 16 + quad * 4 + r;
                float v = acc[nt][r] + b;
                if (relu) v = fmaxf(v, 0.f);
                Ot[m][n] = f_to_bf16(v);
            }
        }
        __syncthreads();
        for (int i = tid; i < 128 * 16; i += 512) {
            int row = i >> 4;
            int c = i & 15;
            int n = node0 + row;
            if (n < N) ((uint4*)outb)[(size_t)n * 16 + c] = *(uint4*)&Ot[row][c * 8];
        }
    }
}

// ---------------- decode fused min (parallel replica fold) ----------------
__global__ void min_out_kernel(const unsigned int* __restrict__ minbuf,
                               const int* __restrict__ flag, void* __restrict__ out) {
    __shared__ unsigned int sh[4][D];
    int tid = threadIdx.x;             // 512 threads
    int q = tid >> 7;
    int c = tid & 127;
    unsigned u = 0xFFFFFFFFu;
    for (int r = q; r < MREP; r += 4) u = min(u, minbuf[r * D + c]);
    sh[q][c] = u;
    __syncthreads();
    if (tid < D) {
        unsigned m = min(min(sh[0][tid], sh[1][tid]), min(sh[2][tid], sh[3][tid]));
        unsigned i = (m & 0x80000000u) ? (m ^ 0x80000000u) : ~m;
        union { unsigned i; float f; } cv; cv.i = i;
        if (flag[1]) ((unsigned short*)out)[tid] = f_to_bf16(cv.f);
        else         ((float*)out)[tid] = cv.f;
    }
}

// ---------------- launch ----------------
extern "C" void kernel_launch(void* const* d_in, const int* in_sizes, int n_in,
                              void* d_out, int out_size, void* d_ws, size_t ws_size,
                              hipStream_t stream) {
    const void* x0   = d_in[0];
    const void* eidx = d_in[1];
    const void* Wl0  = d_in[2];
    const void* bl0  = d_in[3];
    const void* Wr0  = d_in[4];

    const int N = in_sizes[0] / D;          // 100000
    const int E = in_sizes[1] / 2;          // 1600000
    const int L = in_sizes[2] / (D * D);    // 3

    char* ws = (char*)d_ws;
    size_t off = 0;
    auto alloc = [&](size_t bytes) -> void* {
        void* p = ws + off;
        off += (bytes + 255) & ~(size_t)255;
        return p;
    };
    unsigned short* xb    = (unsigned short*)alloc((size_t)N * D * 2);
    unsigned short* bufA  = (unsigned short*)alloc((size_t)N * D * 2);
    unsigned short* meanb = (unsigned short*)alloc((size_t)N * D * 2);
    int*   offsets = (int*)alloc((size_t)(N + 1) * sizeof(int));
    int*   srcs    = (int*)alloc((size_t)E * sizeof(int));
    int*   flag    = (int*)alloc(256);
    unsigned short* Wpack = (unsigned short*)alloc((size_t)L * 8 * 8 * 64 * 8 * 2);
    float* blf     = (float*)alloc((size_t)L * D * sizeof(float));
    unsigned int* minbuf = (unsigned int*)alloc((size_t)MREP * D * sizeof(unsigned int));
    (void)ws_size; (void)n_in; (void)out_size;

    const int NB  = (N + BKT - 1) / BKT;     // 196
    const int EPC = (E + CH - 1) / CH;       // 6250
    const int n2  = NB * CH;                 // 50176
    unsigned int* ebuf = (unsigned int*)meanb;   // aliased: not live during CSR build
    int* counts2D  = (int*)bufA;
    int* bases2D   = counts2D + n2;
    int* blockSums = bases2D + n2;

    detect_kernel<<<1, 1, 0, stream>>>((const unsigned short*)x0, (const int*)eidx, flag);

    prep_kernel<<<561, 256, 0, stream>>>(x0, Wl0, Wr0, bl0, flag,
                                         Wpack, blf, minbuf, xb, L, N * D);

    bucket_hist_kernel<<<CH, 256, 0, stream>>>(eidx, flag, counts2D, E, NB, EPC);
    const int nb2 = (n2 + SCAN_C - 1) / SCAN_C;
    gscan1_kernel<<<nb2, 256, 0, stream>>>(counts2D, blockSums, n2);
    gscan2_kernel<<<1, 256, 0, stream>>>(blockSums, nb2);
    gscan3_kernel<<<nb2, 256, 0, stream>>>(counts2D, blockSums, bases2D, n2);
    bucket_scatter_kernel<<<CH, 256, 0, stream>>>(eidx, flag, bases2D, ebuf, E, NB, EPC);
    bucket_csr_kernel<<<NB, BKT, 0, stream>>>(ebuf, bases2D, offsets, srcs, E, N, NB);

    const unsigned short* cur     = xb;                        // fp32 path: converted copy
    const unsigned short* cur_alt = (const unsigned short*)x0; // bf16 path: raw input
    unsigned short* nxt = bufA;
    for (int l = 0; l < L; ++l) {
        int last = (l == L - 1);
        int agg_blocks = (N * 16 + 255) / 256;
        agg_kernel<<<agg_blocks, 256, 0, stream>>>(cur, cur_alt, flag, offsets, srcs, meanb, N);
        gemm_mfma_kernel<<<(N + 127) / 128, 512, 0, stream>>>(
            meanb, cur, cur_alt, flag, Wpack + (size_t)l * 8 * 8 * 64 * 8, blf + (size_t)l * D,
            nxt, minbuf, N, last ? 0 : 1, last);
        cur = nxt; cur_alt = nxt;
        nxt = (nxt == bufA) ? xb : bufA;
    }

    min_out_kernel<<<1, 512, 0, stream>>>(minbuf, flag, (void*)d_out);
}

// Round 17
// 383.461 us; speedup vs baseline: 1.0397x; 1.0397x over previous
//
#include <hip/hip_runtime.h>
#include <hip/hip_bf16.h>

#define D 128
#define SCAN_C 512
#define BKT 512        // nodes per bucket
#define BKT_SHIFT 9
#define CH 256         // edge chunks
#define NBMAX 512
#define MREP 64        // min-buffer replicas

typedef __attribute__((ext_vector_type(8))) short bf16x8;
typedef __attribute__((ext_vector_type(4))) float f32x4;

// ---------------- bf16 helpers (manual, RN-even) ----------------
__device__ __forceinline__ float bf16_to_f(unsigned int u) {
    union { unsigned int i; float f; } c; c.i = u << 16; return c.f;
}
__device__ __forceinline__ unsigned short f_to_bf16(float f) {
    union { float f; unsigned int i; } c; c.f = f;
    unsigned int r = c.i + 0x7FFFu + ((c.i >> 16) & 1u);
    return (unsigned short)(r >> 16);
}

// ---------------- runtime dtype detection ----------------
__global__ void detect_kernel(const unsigned short* __restrict__ xr,
                              const int* __restrict__ er, int* __restrict__ flag) {
    int plaus = 0;
    for (int i = 0; i < 64; ++i) {
        unsigned short u = xr[2 * i];
        int e = (u >> 7) & 0xFF;
        if (e >= 0x74 && e <= 0x82) plaus++;
    }
    flag[1] = (plaus >= 32) ? 1 : 0;
    int zeros = 0;
    for (int i = 1; i < 128; i += 2) zeros += (er[i] == 0);
    flag[0] = (zeros >= 60) ? 1 : 0;
}

__device__ __forceinline__ int load_idx(const void* p, long long i, int is64) {
    if (is64) return (int)((const long long*)p)[i];
    return ((const int*)p)[i];
}

// ---------------- conversions ----------------
__global__ void cvt_x_kernel(const void* __restrict__ src, const int* __restrict__ flag,
                             unsigned short* __restrict__ dst, int n) {
    if (flag[1]) return;   // bf16 input: no copy needed
    int i = blockIdx.x * blockDim.x + threadIdx.x;
    int stride = gridDim.x * blockDim.x;
    const float* s = (const float*)src;
    for (; i < n; i += stride) dst[i] = f_to_bf16(s[i]);
}

__global__ void cvt_f_kernel(const void* __restrict__ src, const int* __restrict__ flag,
                             float* __restrict__ dst, int n) {
    int is_bf16 = flag[1];
    int i = blockIdx.x * blockDim.x + threadIdx.x;
    int stride = gridDim.x * blockDim.x;
    if (is_bf16) {
        const unsigned short* s = (const unsigned short*)src;
        for (; i < n; i += stride) dst[i] = bf16_to_f(s[i]);
    } else {
        const float* s = (const float*)src;
        for (; i < n; i += stride) dst[i] = s[i];
    }
}

// ---------------- pack W into MFMA B-fragment order ----------------
__global__ void packW_kernel(const void* __restrict__ Wl0, const void* __restrict__ Wr0,
                             const int* __restrict__ flag, unsigned short* __restrict__ Wpack,
                             int L) {
    int idx = blockIdx.x * blockDim.x + threadIdx.x;
    if (idx >= L * 8 * 8 * 64) return;
    int lane = idx & 63;
    int ks = (idx >> 6) & 7;
    int nt = (idx >> 9) & 7;
    int layer = idx >> 12;
    int n = nt * 16 + (lane & 15);
    int k0 = ks * 32 + (lane >> 4) * 8;
    int is_bf16 = flag[1];
    unsigned short outv[8];
#pragma unroll
    for (int j = 0; j < 8; ++j) {
        int k = k0 + j;
        size_t off = (size_t)layer * D * D + (size_t)n * D + (k & 127);
        float v;
        if (is_bf16) {
            const unsigned short* W = (const unsigned short*)((k < D) ? Wl0 : Wr0);
            v = bf16_to_f(W[off]);
        } else {
            const float* W = (const float*)((k < D) ? Wl0 : Wr0);
            v = W[off];
        }
        outv[j] = f_to_bf16(v);
    }
    *(uint4*)&Wpack[(size_t)idx * 8] = *(uint4*)outv;
}

// ---------------- bucketed CSR build ----------------
__global__ void bucket_hist_kernel(const void* __restrict__ eidx, const int* __restrict__ flag,
                                   int* __restrict__ counts2D, int E, int NB, int EPC) {
    __shared__ int hist[NBMAX];
    int c = blockIdx.x;
    for (int i = threadIdx.x; i < NB; i += blockDim.x) hist[i] = 0;
    __syncthreads();
    int is64 = flag[0];
    int end = min(E, (c + 1) * EPC);
    for (int e = c * EPC + threadIdx.x; e < end; e += blockDim.x) {
        int d = load_idx(eidx, (long long)E + e, is64);
        atomicAdd(&hist[d >> BKT_SHIFT], 1);
    }
    __syncthreads();
    for (int i = threadIdx.x; i < NB; i += blockDim.x)
        counts2D[i * CH + c] = hist[i];
}

__global__ void gscan1_kernel(const int* __restrict__ in, int* __restrict__ blockSums, int n) {
    __shared__ int red[256];
    int base = blockIdx.x * SCAN_C;
    int t = threadIdx.x;
    int s = 0;
    if (base + t < n) s += in[base + t];
    if (base + t + 256 < n) s += in[base + t + 256];
    red[t] = s;
    __syncthreads();
    for (int off = 128; off > 0; off >>= 1) {
        if (t < off) red[t] += red[t + off];
        __syncthreads();
    }
    if (t == 0) blockSums[blockIdx.x] = red[0];
}

__global__ void gscan2_kernel(int* __restrict__ blockSums, int nb) {
    __shared__ int sh[256];
    int t = threadIdx.x;
    int orig = (t < nb) ? blockSums[t] : 0;
    sh[t] = orig;
    __syncthreads();
    for (int off = 1; off < 256; off <<= 1) {
        int v = (t >= off) ? sh[t - off] : 0;
        __syncthreads();
        sh[t] += v;
        __syncthreads();
    }
    if (t < nb) blockSums[t] = sh[t] - orig;
}

__global__ void gscan3_kernel(const int* __restrict__ in, const int* __restrict__ blockBase,
                              int* __restrict__ out, int n) {
    __shared__ int sh[SCAN_C];
    int base = blockIdx.x * SCAN_C;
    int t = threadIdx.x;
    int v0 = (base + t < n) ? in[base + t] : 0;
    int v1 = (base + t + 256 < n) ? in[base + t + 256] : 0;
    sh[t] = v0;
    sh[t + 256] = v1;
    __syncthreads();
    for (int off = 1; off < SCAN_C; off <<= 1) {
        int a = (t >= off) ? sh[t - off] : 0;
        int b = (t + 256 >= off) ? sh[t + 256 - off] : 0;
        __syncthreads();
        sh[t] += a;
        sh[t + 256] += b;
        __syncthreads();
    }
    int bb = blockBase[blockIdx.x];
    if (base + t < n) out[base + t] = bb + sh[t] - v0;
    if (base + t + 256 < n) out[base + t + 256] = bb + sh[t + 256] - v1;
}

__global__ void bucket_scatter_kernel(const void* __restrict__ eidx, const int* __restrict__ flag,
                                      const int* __restrict__ bases2D, unsigned int* __restrict__ ebuf,
                                      int E, int NB, int EPC) {
    __shared__ int cur[NBMAX];
    int c = blockIdx.x;
    for (int i = threadIdx.x; i < NB; i += blockDim.x) cur[i] = bases2D[i * CH + c];
    __syncthreads();
    int is64 = flag[0];
    int end = min(E, (c + 1) * EPC);
    for (int e = c * EPC + threadIdx.x; e < end; e += blockDim.x) {
        int s = load_idx(eidx, e, is64);
        int d = load_idx(eidx, (long long)E + e, is64);
        int b = d >> BKT_SHIFT;
        int pos = atomicAdd(&cur[b], 1);
        ebuf[pos] = ((unsigned)s << BKT_SHIFT) | (unsigned)(d & (BKT - 1));
    }
}

__global__ __launch_bounds__(BKT)
void bucket_csr_kernel(const unsigned int* __restrict__ ebuf, const int* __restrict__ bases2D,
                       int* __restrict__ offsets, int* __restrict__ srcs, int E, int N, int NB) {
    __shared__ int lcnt[BKT];
    __shared__ int sh[BKT];
    __shared__ int lcur[BKT];
    int b = blockIdx.x;
    int t = threadIdx.x;
    int start = bases2D[b * CH];
    int end = (b + 1 < NB) ? bases2D[(b + 1) * CH] : E;
    lcnt[t] = 0;
    __syncthreads();
    for (int e = start + t; e < end; e += BKT)
        atomicAdd(&lcnt[ebuf[e] & (BKT - 1)], 1);
    __syncthreads();
    sh[t] = lcnt[t];
    __syncthreads();
    for (int off = 1; off < BKT; off <<= 1) {
        int v = (t >= off) ? sh[t - off] : 0;
        __syncthreads();
        sh[t] += v;
        __syncthreads();
    }
    int excl = sh[t] - lcnt[t];
    int node = b * BKT + t;
    if (node < N) offsets[node] = start + excl;
    lcur[t] = start + excl;
    __syncthreads();
    for (int e = start + t; e < end; e += BKT) {
        unsigned int p = ebuf[e];
        int pos = atomicAdd(&lcur[p & (BKT - 1)], 1);
        srcs[pos] = (int)(p >> BKT_SHIFT);
    }
    if (b == 0 && t == 0) offsets[N] = E;
}

// ---------------- mean aggregation: 1 node per 16-lane group, edge-unroll-4 ----------------
__global__ void agg_kernel(const unsigned short* __restrict__ xmain,
                           const unsigned short* __restrict__ xalt,
                           const int* __restrict__ flag, const int* __restrict__ offsets,
                           const int* __restrict__ srcs, unsigned short* __restrict__ meanb, int N) {
    const unsigned short* xb = flag[1] ? xalt : xmain;
    int g = blockIdx.x * blockDim.x + threadIdx.x;
    int node = g >> 4;
    int lane = g & 15;
    if (node >= N) return;
    int beg = offsets[node], end = offsets[node + 1];
    float acc[8];
#pragma unroll
    for (int i = 0; i < 8; ++i) acc[i] = 0.f;
    const uint4* xp = (const uint4*)xb;

    int j = beg;
    for (; j + 3 < end; j += 4) {
        int s0 = srcs[j];
        int s1 = srcs[j + 1];
        int s2 = srcs[j + 2];
        int s3 = srcs[j + 3];
        uint4 v0 = xp[(size_t)s0 * 16 + lane];
        uint4 v1 = xp[(size_t)s1 * 16 + lane];
        uint4 v2 = xp[(size_t)s2 * 16 + lane];
        uint4 v3 = xp[(size_t)s3 * 16 + lane];
        acc[0] += bf16_to_f(v0.x & 0xFFFFu); acc[1] += bf16_to_f(v0.x >> 16);
        acc[2] += bf16_to_f(v0.y & 0xFFFFu); acc[3] += bf16_to_f(v0.y >> 16);
        acc[4] += bf16_to_f(v0.z & 0xFFFFu); acc[5] += bf16_to_f(v0.z >> 16);
        acc[6] += bf16_to_f(v0.w & 0xFFFFu); acc[7] += bf16_to_f(v0.w >> 16);
        acc[0] += bf16_to_f(v1.x & 0xFFFFu); acc[1] += bf16_to_f(v1.x >> 16);
        acc[2] += bf16_to_f(v1.y & 0xFFFFu); acc[3] += bf16_to_f(v1.y >> 16);
        acc[4] += bf16_to_f(v1.z & 0xFFFFu); acc[5] += bf16_to_f(v1.z >> 16);
        acc[6] += bf16_to_f(v1.w & 0xFFFFu); acc[7] += bf16_to_f(v1.w >> 16);
        acc[0] += bf16_to_f(v2.x & 0xFFFFu); acc[1] += bf16_to_f(v2.x >> 16);
        acc[2] += bf16_to_f(v2.y & 0xFFFFu); acc[3] += bf16_to_f(v2.y >> 16);
        acc[4] += bf16_to_f(v2.z & 0xFFFFu); acc[5] += bf16_to_f(v2.z >> 16);
        acc[6] += bf16_to_f(v2.w & 0xFFFFu); acc[7] += bf16_to_f(v2.w >> 16);
        acc[0] += bf16_to_f(v3.x & 0xFFFFu); acc[1] += bf16_to_f(v3.x >> 16);
        acc[2] += bf16_to_f(v3.y & 0xFFFFu); acc[3] += bf16_to_f(v3.y >> 16);
        acc[4] += bf16_to_f(v3.z & 0xFFFFu); acc[5] += bf16_to_f(v3.z >> 16);
        acc[6] += bf16_to_f(v3.w & 0xFFFFu); acc[7] += bf16_to_f(v3.w >> 16);
    }
    for (; j < end; ++j) {
        uint4 v = xp[(size_t)srcs[j] * 16 + lane];
        acc[0] += bf16_to_f(v.x & 0xFFFFu); acc[1] += bf16_to_f(v.x >> 16);
        acc[2] += bf16_to_f(v.y & 0xFFFFu); acc[3] += bf16_to_f(v.y >> 16);
        acc[4] += bf16_to_f(v.z & 0xFFFFu); acc[5] += bf16_to_f(v.z >> 16);
        acc[6] += bf16_to_f(v.w & 0xFFFFu); acc[7] += bf16_to_f(v.w >> 16);
    }

    float inv = (end > beg) ? 1.0f / (float)(end - beg) : 0.0f;
    uint4 o;
    o.x = (unsigned)f_to_bf16(acc[0] * inv) | ((unsigned)f_to_bf16(acc[1] * inv) << 16);
    o.y = (unsigned)f_to_bf16(acc[2] * inv) | ((unsigned)f_to_bf16(acc[3] * inv) << 16);
    o.z = (unsigned)f_to_bf16(acc[4] * inv) | ((unsigned)f_to_bf16(acc[5] * inv) << 16);
    o.w = (unsigned)f_to_bf16(acc[6] * inv) | ((unsigned)f_to_bf16(acc[7] * inv) << 16);
    ((uint4*)meanb)[(size_t)node * 16 + lane] = o;
}

// ---------------- MFMA dual GEMM, W staged in LDS ----------------
// Block 512 thr (8 waves), 128 rows, 782 blocks (same total wave count as M=16/256thr).
// Wpack (64 KB) staged once per block -> B-fragments via ds_read_b128 (no L2 latency);
// W L2 traffic 400 MB -> 50 MB per dispatch. Store epilogue reuses the W LDS region
// (128x136 Otile = 34.8 KB) after a barrier.
__global__ __launch_bounds__(512)
void gemm_mfma_kernel(const unsigned short* __restrict__ meanb,
                      const unsigned short* __restrict__ xmain,
                      const unsigned short* __restrict__ xalt,
                      const int* __restrict__ flag,
                      const unsigned short* __restrict__ Wpack, const float* __restrict__ bl,
                      unsigned short* __restrict__ outb, unsigned int* __restrict__ minbuf,
                      int N, int relu, int do_min) {
    __shared__ unsigned short Wlds[8 * 8 * 64 * 8];   // 64 KB; aliased as Otile in epilogue
    __shared__ float smin[8][D];
    const unsigned short* xb = flag[1] ? xalt : xmain;

    const int tid = threadIdx.x;
    const int wave = tid >> 6;            // 0..7
    const int lane = tid & 63;
    const int m16 = lane & 15;
    const int quad = lane >> 4;
    const int node0 = blockIdx.x * 128;
    const int arow = node0 + wave * 16 + m16;
    const bool rvalid = arow < N;

    // stage W: 4096 uint4, 512 threads, 8 iters, coalesced
    {
        const uint4* wsrc = (const uint4*)Wpack;
        uint4* wdst = (uint4*)Wlds;
#pragma unroll
        for (int i = 0; i < 8; ++i) wdst[tid + i * 512] = wsrc[tid + i * 512];
    }
    __syncthreads();

    f32x4 acc[8];
#pragma unroll
    for (int i = 0; i < 8; ++i) acc[i] = (f32x4)0.0f;

#pragma unroll
    for (int ks = 0; ks < 8; ++ks) {
        uint4 tmp = make_uint4(0u, 0u, 0u, 0u);
        if (rvalid) {
            const unsigned short* base = (ks < 4)
                ? meanb + (size_t)arow * D + ks * 32 + quad * 8
                : xb    + (size_t)arow * D + (ks - 4) * 32 + quad * 8;
            tmp = *(const uint4*)base;
        }
        bf16x8 afrag = *(bf16x8*)&tmp;
#pragma unroll
        for (int nt = 0; nt < 8; ++nt) {
            bf16x8 bfrag = *(const bf16x8*)&Wlds[((nt * 8 + ks) * 64 + lane) * 8];
            acc[nt] = __builtin_amdgcn_mfma_f32_16x16x32_bf16(afrag, bfrag, acc[nt], 0, 0, 0);
        }
    }

    if (do_min) {
#pragma unroll
        for (int nt = 0; nt < 8; ++nt) {
            int n = nt * 16 + m16;
            float b = bl[n];
            float m = 3.402823466e38f;
#pragma unroll
            for (int r = 0; r < 4; ++r) {
                int node = node0 + wave * 16 + quad * 4 + r;
                float v = (node < N) ? (acc[nt][r] + b) : 3.402823466e38f;
                m = fminf(m, v);
            }
            m = fminf(m, __shfl_xor(m, 16, 64));
            m = fminf(m, __shfl_xor(m, 32, 64));
            if (quad == 0) smin[wave][n] = m;
        }
        __syncthreads();
        if (tid < D) {
            float m = smin[0][tid];
#pragma unroll
            for (int w = 1; w < 8; ++w) m = fminf(m, smin[w][tid]);
            unsigned bits = __float_as_uint(m);
            unsigned enc = ((int)bits >= 0) ? (bits ^ 0x80000000u) : ~bits;
            atomicMin(&minbuf[(blockIdx.x & (MREP - 1)) * D + tid], enc);
        }
        return;
    }

    __syncthreads();   // all ds_reads of Wlds complete before aliasing as Otile
    {
        unsigned short (*Ot)[136] = (unsigned short (*)[136])Wlds;   // 128x136 = 34.8 KB
#pragma unroll
        for (int nt = 0; nt < 8; ++nt) {
            int n = nt * 16 + m16;
            float b = bl[n];
#pragma unroll
            for (int r = 0; r < 4; ++r) {
                int m = wave * 16 + quad * 4 + r;
                float v = acc[nt][r] + b;
                if (relu) v = fmaxf(v, 0.f);
                Ot[m][n] = f_to_bf16(v);
            }
        }
        __syncthreads();
        for (int i = tid; i < 128 * 16; i += 512) {
            int row = i >> 4;
            int c = i & 15;
            int n = node0 + row;
            if (n < N) ((uint4*)outb)[(size_t)n * 16 + c] = *(uint4*)&Ot[row][c * 8];
        }
    }
}

// ---------------- decode fused min (parallel replica fold) ----------------
__global__ void min_out_kernel(const unsigned int* __restrict__ minbuf,
                               const int* __restrict__ flag, void* __restrict__ out) {
    __shared__ unsigned int sh[4][D];
    int tid = threadIdx.x;             // 512 threads
    int q = tid >> 7;
    int c = tid & 127;
    unsigned u = 0xFFFFFFFFu;
    for (int r = q; r < MREP; r += 4) u = min(u, minbuf[r * D + c]);
    sh[q][c] = u;
    __syncthreads();
    if (tid < D) {
        unsigned m = min(min(sh[0][tid], sh[1][tid]), min(sh[2][tid], sh[3][tid]));
        unsigned i = (m & 0x80000000u) ? (m ^ 0x80000000u) : ~m;
        union { unsigned i; float f; } cv; cv.i = i;
        if (flag[1]) ((unsigned short*)out)[tid] = f_to_bf16(cv.f);
        else         ((float*)out)[tid] = cv.f;
    }
}

// ---------------- launch ----------------
extern "C" void kernel_launch(void* const* d_in, const int* in_sizes, int n_in,
                              void* d_out, int out_size, void* d_ws, size_t ws_size,
                              hipStream_t stream) {
    const void* x0   = d_in[0];
    const void* eidx = d_in[1];
    const void* Wl0  = d_in[2];
    const void* bl0  = d_in[3];
    const void* Wr0  = d_in[4];

    const int N = in_sizes[0] / D;          // 100000
    const int E = in_sizes[1] / 2;          // 1600000
    const int L = in_sizes[2] / (D * D);    // 3

    char* ws = (char*)d_ws;
    size_t off = 0;
    auto alloc = [&](size_t bytes) -> void* {
        void* p = ws + off;
        off += (bytes + 255) & ~(size_t)255;
        return p;
    };
    unsigned short* xb    = (unsigned short*)alloc((size_t)N * D * 2);
    unsigned short* bufA  = (unsigned short*)alloc((size_t)N * D * 2);
    unsigned short* meanb = (unsigned short*)alloc((size_t)N * D * 2);
    int*   offsets = (int*)alloc((size_t)(N + 1) * sizeof(int));
    int*   srcs    = (int*)alloc((size_t)E * sizeof(int));
    int*   flag    = (int*)alloc(256);
    unsigned short* Wpack = (unsigned short*)alloc((size_t)L * 8 * 8 * 64 * 8 * 2);
    float* blf     = (float*)alloc((size_t)L * D * sizeof(float));
    unsigned int* minbuf = (unsigned int*)alloc((size_t)MREP * D * sizeof(unsigned int));
    (void)ws_size; (void)n_in; (void)out_size;

    const int NB  = (N + BKT - 1) / BKT;     // 196
    const int EPC = (E + CH - 1) / CH;       // 6250
    const int n2  = NB * CH;                 // 50176
    unsigned int* ebuf = (unsigned int*)meanb;   // aliased: not live during CSR build
    int* counts2D  = (int*)bufA;
    int* bases2D   = counts2D + n2;
    int* blockSums = bases2D + n2;

    detect_kernel<<<1, 1, 0, stream>>>((const unsigned short*)x0, (const int*)eidx, flag);

    cvt_x_kernel<<<2048, 256, 0, stream>>>(x0, flag, xb, N * D);
    cvt_f_kernel<<<8, 256, 0, stream>>>(bl0, flag, blf, L * D);
    packW_kernel<<<(L * 8 * 8 * 64 + 255) / 256, 256, 0, stream>>>(Wl0, Wr0, flag, Wpack, L);

    hipMemsetAsync(minbuf, 0xFF, (size_t)MREP * D * sizeof(unsigned int), stream);

    bucket_hist_kernel<<<CH, 256, 0, stream>>>(eidx, flag, counts2D, E, NB, EPC);
    const int nb2 = (n2 + SCAN_C - 1) / SCAN_C;
    gscan1_kernel<<<nb2, 256, 0, stream>>>(counts2D, blockSums, n2);
    gscan2_kernel<<<1, 256, 0, stream>>>(blockSums, nb2);
    gscan3_kernel<<<nb2, 256, 0, stream>>>(counts2D, blockSums, bases2D, n2);
    bucket_scatter_kernel<<<CH, 256, 0, stream>>>(eidx, flag, bases2D, ebuf, E, NB, EPC);
    bucket_csr_kernel<<<NB, BKT, 0, stream>>>(ebuf, bases2D, offsets, srcs, E, N, NB);

    const unsigned short* cur     = xb;                        // fp32 path: converted copy
    const unsigned short* cur_alt = (const unsigned short*)x0; // bf16 path: raw input
    unsigned short* nxt = bufA;
    for (int l = 0; l < L; ++l) {
        int last = (l == L - 1);
        int agg_blocks = (N * 16 + 255) / 256;
        agg_kernel<<<agg_blocks, 256, 0, stream>>>(cur, cur_alt, flag, offsets, srcs, meanb, N);
        gemm_mfma_kernel<<<(N + 127) / 128, 512, 0, stream>>>(
            meanb, cur, cur_alt, flag, Wpack + (size_t)l * 8 * 8 * 64 * 8, blf + (size_t)l * D,
            nxt, minbuf, N, last ? 0 : 1, last);
        cur = nxt; cur_alt = nxt;
        nxt = (nxt == bufA) ? xb : bufA;
    }

    min_out_kernel<<<1, 512, 0, stream>>>(minbuf, flag, (void*)d_out);
}